// Round 1
// baseline (607.529 us; speedup 1.0000x reference)
//
#include <hip/hip_runtime.h>

// LSTM: B=4096, T=2048, F=1, H=3. Output h_T [4096,3] fp32.
// One thread per batch element; 64-thread blocks -> 64 blocks -> 64 CUs,
// one lone wave per SIMD. Runtime is T * per-step wave issue cost.

#define T_LEN 2048
#define BATCH 4096
#define HID 3

__device__ __forceinline__ float sigm(float x) {
    // sigmoid(x) = 1/(1+exp(-x)) = rcp(1 + exp2(-x*log2(e)))
    float e = __builtin_amdgcn_exp2f(x * -1.44269504088896340736f);
    return __builtin_amdgcn_rcpf(1.0f + e);
}

__device__ __forceinline__ float tanhf_(float x) {
    // tanh(x) = 2*sigmoid(2x) - 1 = 2*rcp(1 + exp2(-2x*log2(e))) - 1
    // Saturates correctly even when exp2 overflows to +inf (rcp(inf)=0).
    float e = __builtin_amdgcn_exp2f(x * -2.88539008177792681472f);
    float r = __builtin_amdgcn_rcpf(1.0f + e);
    return __builtin_fmaf(2.0f, r, -1.0f);
}

__global__ __launch_bounds__(64, 1) void lstm_kernel(
    const float* __restrict__ X,
    const float* __restrict__ Wih,   // [12,1]
    const float* __restrict__ Whh,   // [12,3]
    const float* __restrict__ bih,   // [12]
    const float* __restrict__ bhh,   // [12]
    float* __restrict__ out)         // [4096,3]
{
    const int b = blockIdx.x * blockDim.x + threadIdx.x;  // batch element

    // Wave-uniform weight loads: literal indices on a uniform pointer ->
    // compiler scalarizes to s_load; FMAs become v_fma_f32 v, s, v, v.
    float wih[12], bias[12], whh[12][3];
#pragma unroll
    for (int g = 0; g < 12; ++g) {
        wih[g]  = Wih[g];
        bias[g] = bih[g] + bhh[g];
#pragma unroll
        for (int j = 0; j < 3; ++j) whh[g][j] = Whh[g * 3 + j];
    }

    const float4* xp = (const float4*)(X + (size_t)b * T_LEN);

    float h0 = 0.f, h1 = 0.f, h2 = 0.f;
    float c0 = 0.f, c1 = 0.f, c2 = 0.f;

    float4 cur = xp[0];
    constexpr int T4 = T_LEN / 4;

    for (int t4 = 0; t4 < T4; ++t4) {
        // Prefetch next 4 timesteps before the ~1700-cycle compute body;
        // lone wave has no co-resident waves to hide the miss latency.
        float4 nxt = cur;
        if (t4 + 1 < T4) nxt = xp[t4 + 1];

        float xs[4] = {cur.x, cur.y, cur.z, cur.w};
#pragma unroll
        for (int u = 0; u < 4; ++u) {
            const float x = xs[u];
            float g_[12];
#pragma unroll
            for (int g = 0; g < 12; ++g) {
                float acc = __builtin_fmaf(x, wih[g], bias[g]);
                acc = __builtin_fmaf(h0, whh[g][0], acc);
                acc = __builtin_fmaf(h1, whh[g][1], acc);
                acc = __builtin_fmaf(h2, whh[g][2], acc);
                g_[g] = acc;
            }
            // torch gate order: i, f, g, o
            float i0 = sigm(g_[0]),  i1 = sigm(g_[1]),  i2 = sigm(g_[2]);
            float f0 = sigm(g_[3]),  f1 = sigm(g_[4]),  f2 = sigm(g_[5]);
            float t0 = tanhf_(g_[6]), t1 = tanhf_(g_[7]), t2 = tanhf_(g_[8]);
            float o0 = sigm(g_[9]),  o1 = sigm(g_[10]), o2 = sigm(g_[11]);

            c0 = __builtin_fmaf(f0, c0, i0 * t0);
            c1 = __builtin_fmaf(f1, c1, i1 * t1);
            c2 = __builtin_fmaf(f2, c2, i2 * t2);

            h0 = o0 * tanhf_(c0);
            h1 = o1 * tanhf_(c1);
            h2 = o2 * tanhf_(c2);
        }
        cur = nxt;
    }

    float* op = out + (size_t)b * HID;
    op[0] = h0;
    op[1] = h1;
    op[2] = h2;
}

extern "C" void kernel_launch(void* const* d_in, const int* in_sizes, int n_in,
                              void* d_out, int out_size, void* d_ws, size_t ws_size,
                              hipStream_t stream) {
    const float* X   = (const float*)d_in[0];
    const float* Wih = (const float*)d_in[1];
    const float* Whh = (const float*)d_in[2];
    const float* bih = (const float*)d_in[3];
    const float* bhh = (const float*)d_in[4];
    float* out = (float*)d_out;

    dim3 grid(BATCH / 64);
    dim3 block(64);
    lstm_kernel<<<grid, block, 0, stream>>>(X, Wih, Whh, bih, bhh, out);
}

// Round 2
// 305.210 us; speedup vs baseline: 1.9905x; 1.9905x over previous
//
#include <hip/hip_runtime.h>

// LSTM: B=4096, T=2048, F=1, H=3. Output h_T [4096,3] fp32.
//
// R1 was issue-bound: 64 lone waves at 93% of single-SIMD issue ceiling
// (VALUBusy 5.8% vs 6.25% launch-shape max). R2 splits each batch element
// across a 4-lane quad (one hidden unit per lane; lane 3 duplicates unit 2),
// quadrupling wave count (64 -> 256 SIMDs busy) and cutting per-wave issue
// ~4x. Cross-lane h-broadcast via DPP quad_perm (full-rate VALU, no LDS).

#define T_LEN 2048
#define BATCH 4096

__device__ __forceinline__ float sigm(float x) {
    // sigmoid(x) = rcp(1 + exp2(-x*log2e)); saturates correctly at +/-inf.
    float e = __builtin_amdgcn_exp2f(x * -1.44269504088896340736f);
    return __builtin_amdgcn_rcpf(1.0f + e);
}

__device__ __forceinline__ float tanh_(float x) {
    // tanh(x) = 2*rcp(1 + exp2(-2x*log2e)) - 1; rcp(inf)=0 -> exact -1/+1 sat.
    float e = __builtin_amdgcn_exp2f(x * -2.88539008177792681472f);
    float r = __builtin_amdgcn_rcpf(1.0f + e);
    return __builtin_fmaf(2.0f, r, -1.0f);
}

// Broadcast lane (quad_base + L)'s value to all 4 lanes of the quad.
// quad_perm ctrl: sel0|sel1<<2|sel2<<4|sel3<<6. L=0:0x00 L=1:0x55 L=2:0xAA.
template <int CTRL>
__device__ __forceinline__ float qbcast(float v) {
    int iv = __float_as_int(v);
    int r = __builtin_amdgcn_update_dpp(0, iv, CTRL, 0xf, 0xf, true);
    return __int_as_float(r);
}

__global__ __launch_bounds__(64, 1) void lstm_kernel(
    const float* __restrict__ X,
    const float* __restrict__ Wih,   // [12,1]
    const float* __restrict__ Whh,   // [12,3]
    const float* __restrict__ bih,   // [12]
    const float* __restrict__ bhh,   // [12]
    float* __restrict__ out)         // [4096,3]
{
    const int tid = blockIdx.x * 64 + threadIdx.x;
    const int e = tid >> 2;              // batch element 0..4095
    const int j = tid & 3;               // lane in quad
    const int u = (j < 3) ? j : 2;       // hidden unit (lane 3 duplicates 2)

    // Per-lane gate indices, torch order [i(0..2) f(0..2) g(0..2) o(0..2)].
    const int gi = u, gf = 3 + u, gg = 6 + u, go = 9 + u;

    const float wxi = Wih[gi], wxf = Wih[gf], wxg = Wih[gg], wxo = Wih[go];
    const float bi = bih[gi] + bhh[gi];
    const float bf = bih[gf] + bhh[gf];
    const float bg = bih[gg] + bhh[gg];
    const float bo = bih[go] + bhh[go];
    const float wi0 = Whh[gi * 3 + 0], wi1 = Whh[gi * 3 + 1], wi2 = Whh[gi * 3 + 2];
    const float wf0 = Whh[gf * 3 + 0], wf1 = Whh[gf * 3 + 1], wf2 = Whh[gf * 3 + 2];
    const float wg0 = Whh[gg * 3 + 0], wg1 = Whh[gg * 3 + 1], wg2 = Whh[gg * 3 + 2];
    const float wo0 = Whh[go * 3 + 0], wo1 = Whh[go * 3 + 1], wo2 = Whh[go * 3 + 2];

    // All 4 quad lanes load the same float4 (HW broadcasts same-address).
    const float4* xp = (const float4*)(X + (size_t)e * T_LEN);
    constexpr int T4 = T_LEN / 4;

    // Rolling 3-deep prefetch: ~12 steps (~1300 cyc) ahead covers HBM miss
    // latency — a lone wave per SIMD has no co-resident waves to hide it.
    float4 b0 = xp[0];
    float4 b1 = xp[1];
    float4 b2 = xp[2];

    float h = 0.f, c = 0.f;

    for (int t4 = 0; t4 < T4; ++t4) {
        int nidx = t4 + 3;
        nidx = nidx < T4 ? nidx : T4 - 1;   // branch-free clamp, always valid
        float4 nb = xp[nidx];

        float xs[4] = {b0.x, b0.y, b0.z, b0.w};
#pragma unroll
        for (int s = 0; s < 4; ++s) {
            const float x = xs[s];

            // Broadcast h0,h1,h2 from quad lanes 0,1,2 to all lanes.
            float h0 = qbcast<0x00>(h);
            float h1 = qbcast<0x55>(h);
            float h2 = qbcast<0xAA>(h);

            float ai = __builtin_fmaf(x, wxi, bi);
            float af = __builtin_fmaf(x, wxf, bf);
            float ag = __builtin_fmaf(x, wxg, bg);
            float ao = __builtin_fmaf(x, wxo, bo);
            ai = __builtin_fmaf(h0, wi0, ai);
            af = __builtin_fmaf(h0, wf0, af);
            ag = __builtin_fmaf(h0, wg0, ag);
            ao = __builtin_fmaf(h0, wo0, ao);
            ai = __builtin_fmaf(h1, wi1, ai);
            af = __builtin_fmaf(h1, wf1, af);
            ag = __builtin_fmaf(h1, wg1, ag);
            ao = __builtin_fmaf(h1, wo1, ao);
            ai = __builtin_fmaf(h2, wi2, ai);
            af = __builtin_fmaf(h2, wf2, af);
            ag = __builtin_fmaf(h2, wg2, ag);
            ao = __builtin_fmaf(h2, wo2, ao);

            float iv = sigm(ai);
            float fv = sigm(af);
            float gv = tanh_(ag);
            float ov = sigm(ao);

            c = __builtin_fmaf(fv, c, iv * gv);
            h = ov * tanh_(c);
        }
        b0 = b1; b1 = b2; b2 = nb;
    }

    if (j < 3) out[(size_t)e * 3 + j] = h;
}

extern "C" void kernel_launch(void* const* d_in, const int* in_sizes, int n_in,
                              void* d_out, int out_size, void* d_ws, size_t ws_size,
                              hipStream_t stream) {
    const float* X   = (const float*)d_in[0];
    const float* Wih = (const float*)d_in[1];
    const float* Whh = (const float*)d_in[2];
    const float* bih = (const float*)d_in[3];
    const float* bhh = (const float*)d_in[4];
    float* out = (float*)d_out;

    // 4096 elements x 4 lanes = 16384 threads; 64/block -> 256 blocks,
    // one wave per CU -> 256 SIMDs active (vs 64 in R1).
    dim3 grid(BATCH * 4 / 64);
    dim3 block(64);
    lstm_kernel<<<grid, block, 0, stream>>>(X, Wih, Whh, bih, bhh, out);
}

// Round 3
// 269.297 us; speedup vs baseline: 2.2560x; 1.1334x over previous
//
#include <hip/hip_runtime.h>

// LSTM: B=4096, T=2048, F=1, H=3. Output h_T [4096,3] fp32.
//
// R2 (quad/element, 256 waves): 294 cyc/step = ~150 issue + ~145 exposed
// stalls. Waves are lockstep-identical, so co-residency can't fill stalls;
// only levers are fewer instrs/wave and shorter chains.
// R3: 16 lanes/element (lane = 4*gatetype + unit), 4 elements/wave,
// 1024 waves -> every SIMD on the chip active. Each lane computes ONE gate
// (4 FMAs + uniform-stream activation, 2 trans). Cross-lane via DPP only:
//   gather f,g,o -> unit quad: row_shl:4/8/12
//   replicate h quad0 -> row:  row_shr:4 (bank1), row_shr:8 (banks 2,3)
//   broadcast h0,h1,h2:        quad_perm 0x00/0x55/0xAA

#define T_LEN 2048
#define BATCH 4096

__device__ __forceinline__ float tanh_(float x) {
    // tanh(x) = 2*rcp(1 + exp2(-2x*log2e)) - 1; rcp(inf)=0 -> exact sat.
    float e = __builtin_amdgcn_exp2f(x * -2.88539008177792681472f);
    float r = __builtin_amdgcn_rcpf(1.0f + e);
    return __builtin_fmaf(2.0f, r, -1.0f);
}

template <int CTRL, int RMASK, int BMASK, bool BC>
__device__ __forceinline__ float dppf(float oldv, float src) {
    int r = __builtin_amdgcn_update_dpp(__float_as_int(oldv), __float_as_int(src),
                                        CTRL, RMASK, BMASK, BC);
    return __int_as_float(r);
}

__global__ __launch_bounds__(64, 1) void lstm_kernel(
    const float* __restrict__ X,
    const float* __restrict__ Wih,   // [12,1]
    const float* __restrict__ Whh,   // [12,3]
    const float* __restrict__ bih,   // [12]
    const float* __restrict__ bhh,   // [12]
    float* __restrict__ out)         // [4096,3]
{
    const int lane = threadIdx.x;        // block = 1 wave of 64
    const int row  = lane >> 4;          // element slot within wave (DPP row)
    const int l16  = lane & 15;
    const int gt   = l16 >> 2;           // 0:i 1:f 2:g 3:o  (DPP bank)
    const int u3   = l16 & 3;
    const int u    = (u3 < 3) ? u3 : 2;  // hidden unit; slot 3 duplicates 2
    const int e    = blockIdx.x * 4 + row;
    const int gate = 3 * gt + u;         // torch rows: i 0-2, f 3-5, g 6-8, o 9-11

    // Per-lane weights (divergent loads, preamble only).
    const float wx = Wih[gate];
    const float bb = bih[gate] + bhh[gate];
    const float w0 = Whh[gate * 3 + 0];
    const float w1 = Whh[gate * 3 + 1];
    const float w2 = Whh[gate * 3 + 2];

    // Uniform-stream activation: act(a) = fma(m, rcp(1 + exp2(a*s)), ad)
    //   sigmoid: s=-log2e,  m=1, ad=0;   tanh (g gate): s=-2log2e, m=2, ad=-1
    const bool isg = (gt == 2);
    const float as = isg ? -2.88539008177792681472f : -1.44269504088896340736f;
    const float am = isg ? 2.0f : 1.0f;
    const float ad = isg ? -1.0f : 0.0f;

    // All 16 lanes of a row load the same float4 (HW same-address broadcast).
    const float4* xp = (const float4*)(X + (size_t)e * T_LEN);
    constexpr int T4 = T_LEN / 4;
    float4 b0 = xp[0];
    float4 b1 = xp[1];
    float4 b2 = xp[2];

    float h = 0.f, c = 0.f;
    float h0 = 0.f, h1 = 0.f, h2 = 0.f;

    for (int t4 = 0; t4 < T4; ++t4) {
        int nidx = t4 + 3;
        nidx = nidx < T4 ? nidx : T4 - 1;
        float4 nb = xp[nidx];

        // x-contribution for the 4 sub-steps: independent of h, computed
        // up-front so it schedules into the recurrent chain's stall slots.
        float xa[4];
        xa[0] = __builtin_fmaf(b0.x, wx, bb);
        xa[1] = __builtin_fmaf(b0.y, wx, bb);
        xa[2] = __builtin_fmaf(b0.z, wx, bb);
        xa[3] = __builtin_fmaf(b0.w, wx, bb);

#pragma unroll
        for (int s = 0; s < 4; ++s) {
            // gate preactivation (this lane's single gate)
            float a = __builtin_fmaf(h0, w0, xa[s]);
            a = __builtin_fmaf(h1, w1, a);
            a = __builtin_fmaf(h2, w2, a);

            // activation (sigmoid or tanh via per-lane constants)
            float ee = __builtin_amdgcn_exp2f(a * as);
            float rr = __builtin_amdgcn_rcpf(1.0f + ee);
            float v  = __builtin_fmaf(am, rr, ad);

            // gather f,g,o values onto the unit quad (lanes 0-3 of the row)
            float vf = dppf<0x104, 0xF, 0xF, true>(0.f, v);  // row_shl:4
            float vg = dppf<0x108, 0xF, 0xF, true>(0.f, v);  // row_shl:8
            float vo = dppf<0x10C, 0xF, 0xF, true>(0.f, v);  // row_shl:12

            // c/h update (valid on lanes 0-3; other lanes compute garbage)
            c = __builtin_fmaf(vf, c, v * vg);
            h = vo * tanh_(c);

            // replicate h quad0 across the row, then quad-broadcast h0,h1,h2
            h = dppf<0x114, 0xF, 0x2, false>(h, h);  // row_shr:4 -> bank 1
            h = dppf<0x118, 0xF, 0xC, false>(h, h);  // row_shr:8 -> banks 2,3
            h0 = dppf<0x00, 0xF, 0xF, true>(0.f, h); // quad_perm slot0
            h1 = dppf<0x55, 0xF, 0xF, true>(0.f, h); // quad_perm slot1
            h2 = dppf<0xAA, 0xF, 0xF, true>(0.f, h); // quad_perm slot2
        }
        b0 = b1; b1 = b2; b2 = nb;
    }

    if (l16 < 3) out[(size_t)e * 3 + l16] = h;
}

extern "C" void kernel_launch(void* const* d_in, const int* in_sizes, int n_in,
                              void* d_out, int out_size, void* d_ws, size_t ws_size,
                              hipStream_t stream) {
    const float* X   = (const float*)d_in[0];
    const float* Wih = (const float*)d_in[1];
    const float* Whh = (const float*)d_in[2];
    const float* bih = (const float*)d_in[3];
    const float* bhh = (const float*)d_in[4];
    float* out = (float*)d_out;

    // 4096 elements x 16 lanes = 65536 threads = 1024 waves -> 1024 blocks
    // of 64 -> 4 waves/CU, one per SIMD: every SIMD on the chip active.
    dim3 grid(BATCH / 4);
    dim3 block(64);
    lstm_kernel<<<grid, block, 0, stream>>>(X, Wih, Whh, bih, bhh, out);
}